// Round 2
// 57.054 us; speedup vs baseline: 1.0064x; 1.0064x over previous
//
#include <hip/hip_runtime.h>

// Double-pendulum Hamiltonian dynamics, closed form, fp32 in/out.
// Input y: (B,4) f32 = (th1, th2, p1, p2). Output: (B,4) f32 =
// (dth1, dth2, dp1, dp2) where (M1=M2=L1=L2=1, G=9.81):
//   c = cos(th1-th2), s = sin(th1-th2), det = 2 - c^2
//   dth1 = (p1 - c*p2)/det
//   dth2 = (2*p2 - c*p1)/det
//   dp1  = -s*dth1*dth2 - 2*G*sin(th1)
//   dp2  =  s*dth1*dth2 -   G*sin(th2)
// Derivation: T = 0.5*p^T M^-1 p with M=[[2,c],[c,1]], dT/dc = -dth1*dth2,
// dc/dth1 = -s, dc/dth2 = +s; V = G(3 - 2cos th1 - cos th2).
//
// R2: same plan as R1, with the nontemporal-store compile fix.
// __builtin_nontemporal_store requires a NATIVE clang vector type, not
// HIP's float4 struct — use ext_vector_type(4) + reinterpret_cast.
//  - 2 float4 per thread: both loads issued before either result is
//    consumed (2x memory-level parallelism per lane).
//  - __builtin_amdgcn_rcpf: single v_rcp_f32 instead of __frcp_rn's
//    IEEE divide-refinement chain. Rel err ~1e-5, err budget is 0.63.
//  - nontemporal stores: output is never re-read; skip write-allocate.

#define GCONST 9.81f

typedef float f32x4 __attribute__((ext_vector_type(4)));

__device__ __forceinline__ f32x4 dyn4(f32x4 v) {
    float th1 = v.x;
    float th2 = v.y;
    float p1  = v.z;
    float p2  = v.w;

    float d = th1 - th2;
    float s, c;
    __sincosf(d, &s, &c);          // fast sincos; abs err ~1e-6

    float det = 2.0f - c * c;      // det in [1,2], never singular
    float inv_det = __builtin_amdgcn_rcpf(det);  // raw v_rcp_f32

    float dth1 = (p1 - c * p2) * inv_det;
    float dth2 = (2.0f * p2 - c * p1) * inv_det;

    float cross = s * dth1 * dth2;
    float dp1 = -cross - 2.0f * GCONST * __sinf(th1);
    float dp2 =  cross -        GCONST * __sinf(th2);

    f32x4 r;
    r.x = dth1; r.y = dth2; r.z = dp1; r.w = dp2;
    return r;
}

__global__ __launch_bounds__(256) void pendulum2dof_kernel(
    const f32x4* __restrict__ y, f32x4* __restrict__ out, int n) {
    // Each block owns 512 consecutive float4s; thread t handles
    // base+t and base+t+256 (both wave-coalesced).
    int base = blockIdx.x * 512 + threadIdx.x;
    int i0 = base;
    int i1 = base + 256;

    if (i1 < n) {
        // fast path: both loads in flight before any compute
        f32x4 a = y[i0];
        f32x4 b = y[i1];
        f32x4 ra = dyn4(a);
        f32x4 rb = dyn4(b);
        __builtin_nontemporal_store(ra, &out[i0]);
        __builtin_nontemporal_store(rb, &out[i1]);
    } else if (i0 < n) {
        f32x4 a = y[i0];
        f32x4 ra = dyn4(a);
        __builtin_nontemporal_store(ra, &out[i0]);
    }
}

extern "C" void kernel_launch(void* const* d_in, const int* in_sizes, int n_in,
                              void* d_out, int out_size, void* d_ws, size_t ws_size,
                              hipStream_t stream) {
    // d_in[0] = t (1 elem, unused ODE time); d_in[1] = y (B*4 float32)
    const f32x4* y = (const f32x4*)d_in[1];
    f32x4* out = (f32x4*)d_out;
    int n = in_sizes[1] / 4;  // number of float4 states (B)
    int block = 256;
    int per_block = 512;      // 2 float4 per thread
    int grid = (n + per_block - 1) / per_block;
    pendulum2dof_kernel<<<grid, block, 0, stream>>>(y, out, n);
}